// Round 3
// baseline (836.352 us; speedup 1.0000x reference)
//
#include <hip/hip_runtime.h>
#include <math.h>

#define N_NODES 100000
#define N_EDGES 1600000
#define IN_CH   64
#define GCN_CH  64
#define OUT_CH  32

#define SCAN_BLK   256
#define SCAN_ITEMS 4
#define SCAN_CHUNK (SCAN_BLK * SCAN_ITEMS)              // 1024
#define SCAN_NB    ((N_NODES + SCAN_CHUNK - 1) / SCAN_CHUNK)  // 98

// ---------------------------------------------------------------------------
// 1) fused degree (weighted) + in-degree count histogram over col[]
// ---------------------------------------------------------------------------
__global__ void deg_count_kernel(const int* __restrict__ col, const float* __restrict__ ew,
                                 float* __restrict__ deg_w, int* __restrict__ cnt) {
    int e = blockIdx.x * blockDim.x + threadIdx.x;
    if (e >= N_EDGES) return;
    int c = col[e];
    atomicAdd(&deg_w[c], ew[e]);
    atomicAdd(&cnt[c], 1);
}

// dis[i] = rsqrt(deg_w[i] + 1)   (in place)
__global__ void dis_kernel(float* __restrict__ deg_dis) {
    int i = blockIdx.x * blockDim.x + threadIdx.x;
    if (i < N_NODES) deg_dis[i] = rsqrtf(deg_dis[i] + 1.0f);
}

// ---------------------------------------------------------------------------
// 2) 3-kernel exclusive scan of cnt[N_NODES] -> rowptr[N_NODES+1]
// ---------------------------------------------------------------------------
__global__ void scan1_kernel(const int* __restrict__ cnt, int* __restrict__ rowptr,
                             int* __restrict__ blockSums) {
    __shared__ int sdata[SCAN_BLK];
    int t = threadIdx.x;
    int base = blockIdx.x * SCAN_CHUNK + t * SCAN_ITEMS;
    int v[SCAN_ITEMS];
    int sum = 0;
#pragma unroll
    for (int i = 0; i < SCAN_ITEMS; ++i) {
        int idx = base + i;
        v[i] = (idx < N_NODES) ? cnt[idx] : 0;
        sum += v[i];
    }
    sdata[t] = sum;
    __syncthreads();
    for (int off = 1; off < SCAN_BLK; off <<= 1) {
        int x = (t >= off) ? sdata[t - off] : 0;
        __syncthreads();
        sdata[t] += x;
        __syncthreads();
    }
    int excl = sdata[t] - sum;
    if (t == SCAN_BLK - 1) blockSums[blockIdx.x] = sdata[t];
    int run = excl;
#pragma unroll
    for (int i = 0; i < SCAN_ITEMS; ++i) {
        int idx = base + i;
        if (idx < N_NODES) rowptr[idx] = run;
        run += v[i];
    }
}

__global__ void scan2_kernel(int* __restrict__ blockSums) {
    __shared__ int s[128];
    int t = threadIdx.x;
    int orig = (t < SCAN_NB) ? blockSums[t] : 0;
    s[t] = orig;
    __syncthreads();
    for (int off = 1; off < 128; off <<= 1) {
        int x = (t >= off) ? s[t - off] : 0;
        __syncthreads();
        s[t] += x;
        __syncthreads();
    }
    if (t < SCAN_NB) blockSums[t] = s[t] - orig;
}

__global__ void scan3_kernel(int* __restrict__ rowptr, const int* __restrict__ blockSums) {
    int i = blockIdx.x * blockDim.x + threadIdx.x;
    if (i < N_NODES) rowptr[i] += blockSums[i / SCAN_CHUNK];
    if (i == 0) rowptr[N_NODES] = N_EDGES;
}

// ---------------------------------------------------------------------------
// 3) bucket fill: permute (row, norm) into CSR-by-col order, packed int2.
// ---------------------------------------------------------------------------
__global__ void fill_kernel(const int* __restrict__ row, const int* __restrict__ col,
                            const float* __restrict__ ew, const float* __restrict__ dis,
                            const int* __restrict__ rowptr, int* __restrict__ cnt,
                            int2* __restrict__ edgeRec) {
    int e = blockIdx.x * blockDim.x + threadIdx.x;
    if (e >= N_EDGES) return;
    int r = row[e], c = col[e];
    int k = atomicSub(&cnt[c], 1) - 1;
    int slot = rowptr[c] + k;
    float nv = dis[r] * ew[e] * dis[c];
    edgeRec[slot] = make_int2(r, __float_as_int(nv));
}

// ---------------------------------------------------------------------------
// 4) dense GEMM  Y[N,64] = X[N,64] @ W[64,64]   — float4, 16 rows/block
// ---------------------------------------------------------------------------
__global__ void gemm64_kernel(const float* __restrict__ X, const float* __restrict__ W,
                              float* __restrict__ Y, int nrows) {
    __shared__ float4 Ws[64][16];   // Ws[k][q] = W[k][4q..4q+3]
    int t = threadIdx.x;
    for (int i = t; i < 64 * 16; i += 256)
        ((float4*)Ws)[i] = ((const float4*)W)[i];
    __syncthreads();

    int q   = t & 15;
    int sub = t >> 4;               // 16 rows per block
    int row = blockIdx.x * 16 + sub;
    if (row >= nrows) return;
    const float4* xr = (const float4*)(X + (size_t)row * 64);
    float4 acc = {0.f, 0.f, 0.f, 0.f};
#pragma unroll
    for (int k4 = 0; k4 < 16; ++k4) {
        float4 xv = xr[k4];
#pragma unroll
        for (int j = 0; j < 4; ++j) {
            float xs = (j == 0) ? xv.x : (j == 1) ? xv.y : (j == 2) ? xv.z : xv.w;
            float4 wv = Ws[k4 * 4 + j][q];
            acc.x = fmaf(xs, wv.x, acc.x);
            acc.y = fmaf(xs, wv.y, acc.y);
            acc.z = fmaf(xs, wv.z, acc.z);
            acc.w = fmaf(xs, wv.w, acc.w);
        }
    }
    *(float4*)(Y + (size_t)row * 64 + q * 4) = acc;
}

// ---------------------------------------------------------------------------
// 5) fused gather + self-loop + bias + relu.
//    One wave per node. Lane = (edge-group g = lane>>4) x (channel-quad q = lane&15).
//    4 edges in flight per iteration, float4 per lane.
// ---------------------------------------------------------------------------
__global__ void gather_fused_kernel(const int* __restrict__ rowptr,
                                    const int2* __restrict__ edgeRec,
                                    const float* __restrict__ XW,
                                    const float* __restrict__ dis, const float* __restrict__ b,
                                    float* __restrict__ H) {
    int node = blockIdx.x * (blockDim.x >> 6) + (threadIdx.x >> 6);
    if (node >= N_NODES) return;
    int lane = threadIdx.x & 63;
    int g = lane >> 4;          // edge group 0..3
    int q = lane & 15;          // channel quad
    int beg = rowptr[node], end = rowptr[node + 1];

    float4 acc = {0.f, 0.f, 0.f, 0.f};
    for (int s = beg; s + g < end; s += 4) {
        int2  rec = edgeRec[s + g];                 // broadcast within group
        float nv  = __int_as_float(rec.y);
        float4 xv = *(const float4*)(XW + (size_t)rec.x * 64 + q * 4);
        acc.x = fmaf(nv, xv.x, acc.x);
        acc.y = fmaf(nv, xv.y, acc.y);
        acc.z = fmaf(nv, xv.z, acc.z);
        acc.w = fmaf(nv, xv.w, acc.w);
    }
    // reduce across the 4 edge-groups (lane bits 4 and 5)
    acc.x += __shfl_xor(acc.x, 16, 64);
    acc.y += __shfl_xor(acc.y, 16, 64);
    acc.z += __shfl_xor(acc.z, 16, 64);
    acc.w += __shfl_xor(acc.w, 16, 64);
    acc.x += __shfl_xor(acc.x, 32, 64);
    acc.y += __shfl_xor(acc.y, 32, 64);
    acc.z += __shfl_xor(acc.z, 32, 64);
    acc.w += __shfl_xor(acc.w, 32, 64);

    if (g == 0) {
        float d  = dis[node];
        float dd = d * d;
        float4 xs = *(const float4*)(XW + (size_t)node * 64 + q * 4);
        float4 bb = *(const float4*)(b + q * 4);
        float4 v;
        v.x = fmaxf(fmaf(dd, xs.x, acc.x) + bb.x, 0.f);
        v.y = fmaxf(fmaf(dd, xs.y, acc.y) + bb.y, 0.f);
        v.z = fmaxf(fmaf(dd, xs.z, acc.z) + bb.z, 0.f);
        v.w = fmaxf(fmaf(dd, xs.w, acc.w) + bb.w, 0.f);
        *(float4*)(H + (size_t)node * 64 + q * 4) = v;
    }
}

// ---------------------------------------------------------------------------
// 6) output GEMM + bias + tanh — float4, 32 rows/block
// ---------------------------------------------------------------------------
__global__ void out_gemm_kernel(const float* __restrict__ H, const float* __restrict__ W,
                                const float* __restrict__ b, float* __restrict__ Y) {
    __shared__ float4 Ws[64][8];    // Ws[k][q] = W[k][4q..4q+3]
    int t = threadIdx.x;
    for (int i = t; i < 64 * 8; i += 256)
        ((float4*)Ws)[i] = ((const float4*)W)[i];
    __syncthreads();

    int q   = t & 7;
    int sub = t >> 3;               // 32 rows per block
    int row = blockIdx.x * 32 + sub;
    if (row >= N_NODES) return;
    const float4* hr = (const float4*)(H + (size_t)row * 64);
    float4 bb = *(const float4*)(b + q * 4);
    float4 acc = bb;
#pragma unroll
    for (int k4 = 0; k4 < 16; ++k4) {
        float4 xv = hr[k4];
#pragma unroll
        for (int j = 0; j < 4; ++j) {
            float xs = (j == 0) ? xv.x : (j == 1) ? xv.y : (j == 2) ? xv.z : xv.w;
            float4 wv = Ws[k4 * 4 + j][q];
            acc.x = fmaf(xs, wv.x, acc.x);
            acc.y = fmaf(xs, wv.y, acc.y);
            acc.z = fmaf(xs, wv.z, acc.z);
            acc.w = fmaf(xs, wv.w, acc.w);
        }
    }
    float4 v;
    v.x = tanhf(acc.x);
    v.y = tanhf(acc.y);
    v.z = tanhf(acc.z);
    v.w = tanhf(acc.w);
    *(float4*)(Y + (size_t)row * OUT_CH + q * 4) = v;
}

// ---------------------------------------------------------------------------
extern "C" void kernel_launch(void* const* d_in, const int* in_sizes, int n_in,
                              void* d_out, int out_size, void* d_ws, size_t ws_size,
                              hipStream_t stream) {
    const float* x     = (const float*)d_in[0];
    const int*   eidx  = (const int*)  d_in[1];
    const float* ew    = (const float*)d_in[2];
    const float* W1    = (const float*)d_in[3];
    const float* b1    = (const float*)d_in[4];
    const float* W2    = (const float*)d_in[5];
    const float* b2    = (const float*)d_in[6];
    const float* Wout  = (const float*)d_in[7];
    const float* bout  = (const float*)d_in[8];
    float*       out   = (float*)d_out;

    const int* row = eidx;             // edge_index[0]
    const int* col = eidx + N_EDGES;   // edge_index[1]

    // workspace layout
    char*  ws   = (char*)d_ws;
    size_t offs = 0;
    auto alloc = [&](size_t bytes) {
        char* p = ws + offs;
        offs += (bytes + 1023) & ~(size_t)1023;
        return p;
    };
    float* dis       = (float*)alloc((size_t)N_NODES * sizeof(float));
    int*   cnt       = (int*)  alloc((size_t)N_NODES * sizeof(int));
    int*   rowptr    = (int*)  alloc((size_t)(N_NODES + 1) * sizeof(int));
    int*   blockSums = (int*)  alloc((size_t)SCAN_NB * sizeof(int));
    int2*  edgeRec   = (int2*) alloc((size_t)N_EDGES * sizeof(int2));
    float* xw        = (float*)alloc((size_t)N_NODES * GCN_CH * sizeof(float));
    float* h         = (float*)alloc((size_t)N_NODES * GCN_CH * sizeof(float));

    const int BLK = 256;
    const int gEdges  = (N_EDGES + BLK - 1) / BLK;
    const int gNodes  = (N_NODES + BLK - 1) / BLK;
    const int gGemm64 = (N_NODES + 15) / 16;   // 16 rows/block
    const int gGather = (N_NODES + 3) / 4;     // 4 nodes/block (1 wave each)
    const int gOut    = (N_NODES + 31) / 32;   // 32 rows/block

    // ---- graph preprocessing (once per call, shared by both layers) ----
    hipMemsetAsync(dis, 0, (size_t)N_NODES * sizeof(float), stream);
    hipMemsetAsync(cnt, 0, (size_t)N_NODES * sizeof(int), stream);
    deg_count_kernel<<<gEdges, BLK, 0, stream>>>(col, ew, dis, cnt);
    dis_kernel<<<gNodes, BLK, 0, stream>>>(dis);
    scan1_kernel<<<SCAN_NB, SCAN_BLK, 0, stream>>>(cnt, rowptr, blockSums);
    scan2_kernel<<<1, 128, 0, stream>>>(blockSums);
    scan3_kernel<<<gNodes, BLK, 0, stream>>>(rowptr, blockSums);
    fill_kernel<<<gEdges, BLK, 0, stream>>>(row, col, ew, dis, rowptr, cnt, edgeRec);

    // ---- layer 1 ----
    gemm64_kernel<<<gGemm64, BLK, 0, stream>>>(x, W1, xw, N_NODES);
    gather_fused_kernel<<<gGather, BLK, 0, stream>>>(rowptr, edgeRec, xw, dis, b1, h);

    // ---- layer 2 ----
    gemm64_kernel<<<gGemm64, BLK, 0, stream>>>(h, W2, xw, N_NODES);
    gather_fused_kernel<<<gGather, BLK, 0, stream>>>(rowptr, edgeRec, xw, dis, b2, h);

    // ---- output projection ----
    out_gemm_kernel<<<gOut, BLK, 0, stream>>>(h, Wout, bout, out);
}

// Round 4
// 437.329 us; speedup vs baseline: 1.9124x; 1.9124x over previous
//
#include <hip/hip_runtime.h>
#include <math.h>

#define N_NODES 100000
#define N_EDGES 1600000
#define IN_CH   64
#define GCN_CH  64
#define OUT_CH  32

#define SCAN_BLK   256
#define SCAN_ITEMS 4
#define SCAN_CHUNK (SCAN_BLK * SCAN_ITEMS)              // 1024
#define SCAN_NB    ((N_NODES + SCAN_CHUNK - 1) / SCAN_CHUNK)  // 98

// ---------------------------------------------------------------------------
// 1) fused degree (weighted) + in-degree count histogram over col[]
// ---------------------------------------------------------------------------
__global__ void deg_count_kernel(const int* __restrict__ col, const float* __restrict__ ew,
                                 float* __restrict__ deg_w, int* __restrict__ cnt) {
    int e = blockIdx.x * blockDim.x + threadIdx.x;
    if (e >= N_EDGES) return;
    int c = col[e];
    atomicAdd(&deg_w[c], ew[e]);
    atomicAdd(&cnt[c], 1);
}

// ---------------------------------------------------------------------------
// 2) scan of cnt -> rowptr (exclusive);  scan1 also does dis = rsqrt(deg+1)
// ---------------------------------------------------------------------------
__global__ void scan1_kernel(const int* __restrict__ cnt, int* __restrict__ rowptr,
                             int* __restrict__ blockSums, float* __restrict__ deg_dis) {
    __shared__ int sdata[SCAN_BLK];
    int t = threadIdx.x;
    int base = blockIdx.x * SCAN_CHUNK + t * SCAN_ITEMS;
    int v[SCAN_ITEMS];
    int sum = 0;
#pragma unroll
    for (int i = 0; i < SCAN_ITEMS; ++i) {
        int idx = base + i;
        v[i] = (idx < N_NODES) ? cnt[idx] : 0;
        sum += v[i];
        if (idx < N_NODES) deg_dis[idx] = rsqrtf(deg_dis[idx] + 1.0f);
    }
    sdata[t] = sum;
    __syncthreads();
    for (int off = 1; off < SCAN_BLK; off <<= 1) {
        int x = (t >= off) ? sdata[t - off] : 0;
        __syncthreads();
        sdata[t] += x;
        __syncthreads();
    }
    int excl = sdata[t] - sum;
    if (t == SCAN_BLK - 1) blockSums[blockIdx.x] = sdata[t];
    int run = excl;
#pragma unroll
    for (int i = 0; i < SCAN_ITEMS; ++i) {
        int idx = base + i;
        if (idx < N_NODES) rowptr[idx] = run;
        run += v[i];
    }
}

__global__ void scan2_kernel(int* __restrict__ blockSums) {
    __shared__ int s[128];
    int t = threadIdx.x;
    int orig = (t < SCAN_NB) ? blockSums[t] : 0;
    s[t] = orig;
    __syncthreads();
    for (int off = 1; off < 128; off <<= 1) {
        int x = (t >= off) ? s[t - off] : 0;
        __syncthreads();
        s[t] += x;
        __syncthreads();
    }
    if (t < SCAN_NB) blockSums[t] = s[t] - orig;
}

__global__ void scan3_kernel(int* __restrict__ rowptr, const int* __restrict__ blockSums) {
    int i = blockIdx.x * blockDim.x + threadIdx.x;
    if (i < N_NODES) rowptr[i] += blockSums[i / SCAN_CHUNK];
    if (i == 0) rowptr[N_NODES] = N_EDGES;
}

// ---------------------------------------------------------------------------
// 3) bucket fill: permute (row, norm) into CSR-by-col order, packed int2.
// ---------------------------------------------------------------------------
__global__ void fill_kernel(const int* __restrict__ row, const int* __restrict__ col,
                            const float* __restrict__ ew, const float* __restrict__ dis,
                            const int* __restrict__ rowptr, int* __restrict__ cnt,
                            int2* __restrict__ edgeRec) {
    int e = blockIdx.x * blockDim.x + threadIdx.x;
    if (e >= N_EDGES) return;
    int r = row[e], c = col[e];
    int k = atomicSub(&cnt[c], 1) - 1;
    int slot = rowptr[c] + k;
    float nv = dis[r] * ew[e] * dis[c];
    edgeRec[slot] = make_int2(r, __float_as_int(nv));
}

// ---------------------------------------------------------------------------
// 4) dense GEMM  Y[N,64] = X[N,64] @ W[64,64]   — float4, 16 rows/block
// ---------------------------------------------------------------------------
__global__ void gemm64_kernel(const float* __restrict__ X, const float* __restrict__ W,
                              float* __restrict__ Y, int nrows) {
    __shared__ float4 Ws[64][16];   // Ws[k][q] = W[k][4q..4q+3]
    int t = threadIdx.x;
    for (int i = t; i < 64 * 16; i += 256)
        ((float4*)Ws)[i] = ((const float4*)W)[i];
    __syncthreads();

    int q   = t & 15;
    int sub = t >> 4;               // 16 rows per block
    int row = blockIdx.x * 16 + sub;
    if (row >= nrows) return;
    const float4* xr = (const float4*)(X + (size_t)row * 64);
    float4 acc = {0.f, 0.f, 0.f, 0.f};
#pragma unroll
    for (int k4 = 0; k4 < 16; ++k4) {
        float4 xv = xr[k4];
#pragma unroll
        for (int j = 0; j < 4; ++j) {
            float xs = (j == 0) ? xv.x : (j == 1) ? xv.y : (j == 2) ? xv.z : xv.w;
            float4 wv = Ws[k4 * 4 + j][q];
            acc.x = fmaf(xs, wv.x, acc.x);
            acc.y = fmaf(xs, wv.y, acc.y);
            acc.z = fmaf(xs, wv.z, acc.z);
            acc.w = fmaf(xs, wv.w, acc.w);
        }
    }
    *(float4*)(Y + (size_t)row * 64 + q * 4) = acc;
}

// ---------------------------------------------------------------------------
// 5a) layer-1 gather + self-loop + bias + relu -> H
//     One wave per node. lane = (edge-group g = lane>>4) x (channel-quad q = lane&15)
// ---------------------------------------------------------------------------
__global__ void gather_l1_kernel(const int* __restrict__ rowptr,
                                 const int2* __restrict__ edgeRec,
                                 const float* __restrict__ XW,
                                 const float* __restrict__ dis, const float* __restrict__ b,
                                 float* __restrict__ H) {
    int node = blockIdx.x * (blockDim.x >> 6) + (threadIdx.x >> 6);
    if (node >= N_NODES) return;
    int lane = threadIdx.x & 63;
    int g = lane >> 4;
    int q = lane & 15;
    int beg = rowptr[node], end = rowptr[node + 1];

    float4 acc = {0.f, 0.f, 0.f, 0.f};
    for (int s = beg; s + g < end; s += 4) {
        int2  rec = edgeRec[s + g];
        float nv  = __int_as_float(rec.y);
        float4 xv = *(const float4*)(XW + (size_t)rec.x * 64 + q * 4);
        acc.x = fmaf(nv, xv.x, acc.x);
        acc.y = fmaf(nv, xv.y, acc.y);
        acc.z = fmaf(nv, xv.z, acc.z);
        acc.w = fmaf(nv, xv.w, acc.w);
    }
    acc.x += __shfl_xor(acc.x, 16, 64);
    acc.y += __shfl_xor(acc.y, 16, 64);
    acc.z += __shfl_xor(acc.z, 16, 64);
    acc.w += __shfl_xor(acc.w, 16, 64);
    acc.x += __shfl_xor(acc.x, 32, 64);
    acc.y += __shfl_xor(acc.y, 32, 64);
    acc.z += __shfl_xor(acc.z, 32, 64);
    acc.w += __shfl_xor(acc.w, 32, 64);

    if (g == 0) {
        float d  = dis[node];
        float dd = d * d;
        float4 xs = *(const float4*)(XW + (size_t)node * 64 + q * 4);
        float4 bb = *(const float4*)(b + q * 4);
        float4 v;
        v.x = fmaxf(fmaf(dd, xs.x, acc.x) + bb.x, 0.f);
        v.y = fmaxf(fmaf(dd, xs.y, acc.y) + bb.y, 0.f);
        v.z = fmaxf(fmaf(dd, xs.z, acc.z) + bb.z, 0.f);
        v.w = fmaxf(fmaf(dd, xs.w, acc.w) + bb.w, 0.f);
        *(float4*)(H + (size_t)node * 64 + q * 4) = v;
    }
}

// ---------------------------------------------------------------------------
// 5b) layer-2 gather + self-loop + bias + relu + (h @ Wout + bout) + tanh -> OUT
//     Same edge loop; after the xor-reduction ALL lanes hold the h-quad for
//     their q, so the 64x32 matvec is done in-register via shfl broadcasts.
// ---------------------------------------------------------------------------
__global__ void gather_out_kernel(const int* __restrict__ rowptr,
                                  const int2* __restrict__ edgeRec,
                                  const float* __restrict__ XW,
                                  const float* __restrict__ dis, const float* __restrict__ b,
                                  const float* __restrict__ Wout, const float* __restrict__ bout,
                                  float* __restrict__ OUT) {
    __shared__ float Ws[64][OUT_CH];          // Ws[k][j] = Wout[k][j], 8 KB
    {
        int t = threadIdx.x;
        for (int i = t; i < 64 * OUT_CH / 4; i += 256)
            ((float4*)Ws)[i] = ((const float4*)Wout)[i];
        __syncthreads();
    }

    int node = blockIdx.x * (blockDim.x >> 6) + (threadIdx.x >> 6);
    if (node >= N_NODES) return;
    int lane = threadIdx.x & 63;
    int g = lane >> 4;
    int q = lane & 15;
    int beg = rowptr[node], end = rowptr[node + 1];

    float4 acc = {0.f, 0.f, 0.f, 0.f};
    for (int s = beg; s + g < end; s += 4) {
        int2  rec = edgeRec[s + g];
        float nv  = __int_as_float(rec.y);
        float4 xv = *(const float4*)(XW + (size_t)rec.x * 64 + q * 4);
        acc.x = fmaf(nv, xv.x, acc.x);
        acc.y = fmaf(nv, xv.y, acc.y);
        acc.z = fmaf(nv, xv.z, acc.z);
        acc.w = fmaf(nv, xv.w, acc.w);
    }
    acc.x += __shfl_xor(acc.x, 16, 64);
    acc.y += __shfl_xor(acc.y, 16, 64);
    acc.z += __shfl_xor(acc.z, 16, 64);
    acc.w += __shfl_xor(acc.w, 16, 64);
    acc.x += __shfl_xor(acc.x, 32, 64);
    acc.y += __shfl_xor(acc.y, 32, 64);
    acc.z += __shfl_xor(acc.z, 32, 64);
    acc.w += __shfl_xor(acc.w, 32, 64);

    // every lane now holds the reduced quad for channels 4q..4q+3
    float d  = dis[node];
    float dd = d * d;
    float4 xs = *(const float4*)(XW + (size_t)node * 64 + q * 4);
    float4 bb = *(const float4*)(b + q * 4);
    float4 h;
    h.x = fmaxf(fmaf(dd, xs.x, acc.x) + bb.x, 0.f);
    h.y = fmaxf(fmaf(dd, xs.y, acc.y) + bb.y, 0.f);
    h.z = fmaxf(fmaf(dd, xs.z, acc.z) + bb.z, 0.f);
    h.w = fmaxf(fmaf(dd, xs.w, acc.w) + bb.w, 0.f);

    // 64x32 matvec: lane L computes out[L&31] over k-half (L>>5)
    int j    = lane & 31;
    int half = lane >> 5;                     // 0: k=0..31, 1: k=32..63
    float partial = 0.f;
#pragma unroll
    for (int p = 0; p < 8; ++p) {
        int qp = half * 8 + p;                // source channel-quad
        float hx = __shfl(h.x, qp, 64);
        float hy = __shfl(h.y, qp, 64);
        float hz = __shfl(h.z, qp, 64);
        float hw = __shfl(h.w, qp, 64);
        int k = qp * 4;
        partial = fmaf(hx, Ws[k + 0][j], partial);
        partial = fmaf(hy, Ws[k + 1][j], partial);
        partial = fmaf(hz, Ws[k + 2][j], partial);
        partial = fmaf(hw, Ws[k + 3][j], partial);
    }
    partial += __shfl_xor(partial, 32, 64);
    if (lane < 32) {
        OUT[(size_t)node * OUT_CH + lane] = tanhf(partial + bout[lane]);
    }
}

// ---------------------------------------------------------------------------
extern "C" void kernel_launch(void* const* d_in, const int* in_sizes, int n_in,
                              void* d_out, int out_size, void* d_ws, size_t ws_size,
                              hipStream_t stream) {
    const float* x     = (const float*)d_in[0];
    const int*   eidx  = (const int*)  d_in[1];
    const float* ew    = (const float*)d_in[2];
    const float* W1    = (const float*)d_in[3];
    const float* b1    = (const float*)d_in[4];
    const float* W2    = (const float*)d_in[5];
    const float* b2    = (const float*)d_in[6];
    const float* Wout  = (const float*)d_in[7];
    const float* bout  = (const float*)d_in[8];
    float*       out   = (float*)d_out;

    const int* row = eidx;             // edge_index[0]
    const int* col = eidx + N_EDGES;   // edge_index[1]

    // workspace layout
    char*  ws   = (char*)d_ws;
    size_t offs = 0;
    auto alloc = [&](size_t bytes) {
        char* p = ws + offs;
        offs += (bytes + 1023) & ~(size_t)1023;
        return p;
    };
    float* dis       = (float*)alloc((size_t)N_NODES * sizeof(float));
    int*   cnt       = (int*)  alloc((size_t)N_NODES * sizeof(int));
    int*   rowptr    = (int*)  alloc((size_t)(N_NODES + 1) * sizeof(int));
    int*   blockSums = (int*)  alloc((size_t)SCAN_NB * sizeof(int));
    int2*  edgeRec   = (int2*) alloc((size_t)N_EDGES * sizeof(int2));
    float* xw        = (float*)alloc((size_t)N_NODES * GCN_CH * sizeof(float));
    float* h         = (float*)alloc((size_t)N_NODES * GCN_CH * sizeof(float));

    const int BLK = 256;
    const int gEdges  = (N_EDGES + BLK - 1) / BLK;
    const int gNodes  = (N_NODES + BLK - 1) / BLK;
    const int gGemm64 = (N_NODES + 15) / 16;   // 16 rows/block
    const int gGather = (N_NODES + 3) / 4;     // 4 nodes/block (1 wave each)

    // ---- graph preprocessing (once per call, shared by both layers) ----
    hipMemsetAsync(dis, 0, (size_t)N_NODES * sizeof(float), stream);
    hipMemsetAsync(cnt, 0, (size_t)N_NODES * sizeof(int), stream);
    deg_count_kernel<<<gEdges, BLK, 0, stream>>>(col, ew, dis, cnt);
    scan1_kernel<<<SCAN_NB, SCAN_BLK, 0, stream>>>(cnt, rowptr, blockSums, dis);
    scan2_kernel<<<1, 128, 0, stream>>>(blockSums);
    scan3_kernel<<<gNodes, BLK, 0, stream>>>(rowptr, blockSums);
    fill_kernel<<<gEdges, BLK, 0, stream>>>(row, col, ew, dis, rowptr, cnt, edgeRec);

    // ---- layer 1 ----
    gemm64_kernel<<<gGemm64, BLK, 0, stream>>>(x, W1, xw, N_NODES);
    gather_l1_kernel<<<gGather, BLK, 0, stream>>>(rowptr, edgeRec, xw, dis, b1, h);

    // ---- layer 2 (gather fused with output projection) ----
    gemm64_kernel<<<gGemm64, BLK, 0, stream>>>(h, W2, xw, N_NODES);
    gather_out_kernel<<<gGather, BLK, 0, stream>>>(rowptr, edgeRec, xw, dis, b2,
                                                   Wout, bout, out);
}

// Round 5
// 365.042 us; speedup vs baseline: 2.2911x; 1.1980x over previous
//
#include <hip/hip_runtime.h>
#include <math.h>

#define N_NODES 100000
#define N_EDGES 1600000
#define IN_CH   64
#define GCN_CH  64
#define OUT_CH  32

#define CNT_SHIFT 42
#define W_SCALE   67108864.0f          // 2^26
#define W_INV     (1.0f / 67108864.0f)

#define SCAN_BLK   256
#define SCAN_ITEMS 4
#define SCAN_CHUNK (SCAN_BLK * SCAN_ITEMS)              // 1024
#define SCAN_NB    ((N_NODES + SCAN_CHUNK - 1) / SCAN_CHUNK)  // 98

// ---------------------------------------------------------------------------
// 1) fused histogram: packed[c] += (1<<42) | round(ew * 2^26)
//    ONE 64-bit atomic per edge (count in high bits, fixed-point weight low)
// ---------------------------------------------------------------------------
__global__ void deg_pack_kernel(const int* __restrict__ col, const float* __restrict__ ew,
                                unsigned long long* __restrict__ packed) {
    int e = blockIdx.x * blockDim.x + threadIdx.x;
    if (e >= N_EDGES) return;
    int c = col[e];
    unsigned long long w = (unsigned long long)(ew[e] * W_SCALE + 0.5f);
    atomicAdd(&packed[c], (1ULL << CNT_SHIFT) | w);
}

// ---------------------------------------------------------------------------
// 2) scan of counts -> rowptr (exclusive); also dis = rsqrt(weight + 1)
// ---------------------------------------------------------------------------
__global__ void scan1_kernel(const unsigned long long* __restrict__ packed,
                             int* __restrict__ rowptr, int* __restrict__ blockSums,
                             float* __restrict__ dis) {
    __shared__ int sdata[SCAN_BLK];
    int t = threadIdx.x;
    int base = blockIdx.x * SCAN_CHUNK + t * SCAN_ITEMS;
    int v[SCAN_ITEMS];
    int sum = 0;
#pragma unroll
    for (int i = 0; i < SCAN_ITEMS; ++i) {
        int idx = base + i;
        unsigned long long p = (idx < N_NODES) ? packed[idx] : 0ULL;
        v[i] = (int)(p >> CNT_SHIFT);
        sum += v[i];
        if (idx < N_NODES) {
            float deg = (float)(p & ((1ULL << CNT_SHIFT) - 1)) * W_INV;
            dis[idx] = rsqrtf(deg + 1.0f);
        }
    }
    sdata[t] = sum;
    __syncthreads();
    for (int off = 1; off < SCAN_BLK; off <<= 1) {
        int x = (t >= off) ? sdata[t - off] : 0;
        __syncthreads();
        sdata[t] += x;
        __syncthreads();
    }
    int excl = sdata[t] - sum;
    if (t == SCAN_BLK - 1) blockSums[blockIdx.x] = sdata[t];
    int run = excl;
#pragma unroll
    for (int i = 0; i < SCAN_ITEMS; ++i) {
        int idx = base + i;
        if (idx < N_NODES) rowptr[idx] = run;
        run += v[i];
    }
}

__global__ void scan2_kernel(int* __restrict__ blockSums) {
    __shared__ int s[128];
    int t = threadIdx.x;
    int orig = (t < SCAN_NB) ? blockSums[t] : 0;
    s[t] = orig;
    __syncthreads();
    for (int off = 1; off < 128; off <<= 1) {
        int x = (t >= off) ? s[t - off] : 0;
        __syncthreads();
        s[t] += x;
        __syncthreads();
    }
    if (t < SCAN_NB) blockSums[t] = s[t] - orig;
}

__global__ void scan3_kernel(int* __restrict__ rowptr, const int* __restrict__ blockSums) {
    int i = blockIdx.x * blockDim.x + threadIdx.x;
    if (i < N_NODES) rowptr[i] += blockSums[i / SCAN_CHUNK];
    if (i == 0) rowptr[N_NODES] = N_EDGES;
}

// ---------------------------------------------------------------------------
// 3) bucket fill: cursor = count field of packed (decrement by 1<<42;
//    exact multiple of 2^42 -> low bits never borrowed).
// ---------------------------------------------------------------------------
__global__ void fill_kernel(const int* __restrict__ row, const int* __restrict__ col,
                            const float* __restrict__ ew, const float* __restrict__ dis,
                            const int* __restrict__ rowptr,
                            unsigned long long* __restrict__ packed,
                            int2* __restrict__ edgeRec) {
    int e = blockIdx.x * blockDim.x + threadIdx.x;
    if (e >= N_EDGES) return;
    int r = row[e], c = col[e];
    unsigned long long old =
        atomicAdd(&packed[c], (unsigned long long)(-(long long)(1ULL << CNT_SHIFT)));
    int k = (int)(old >> CNT_SHIFT) - 1;
    int slot = rowptr[c] + k;
    float nv = dis[r] * ew[e] * dis[c];
    edgeRec[slot] = make_int2(r, __float_as_int(nv));
}

// ---------------------------------------------------------------------------
// 4) dense GEMM  Y[N,64] = X[N,64] @ W[64,64]   — float4, 16 rows/block
// ---------------------------------------------------------------------------
__global__ void gemm64_kernel(const float* __restrict__ X, const float* __restrict__ W,
                              float* __restrict__ Y, int nrows) {
    __shared__ float4 Ws[64][16];   // Ws[k][q] = W[k][4q..4q+3]
    int t = threadIdx.x;
    for (int i = t; i < 64 * 16; i += 256)
        ((float4*)Ws)[i] = ((const float4*)W)[i];
    __syncthreads();

    int q   = t & 15;
    int sub = t >> 4;               // 16 rows per block
    int row = blockIdx.x * 16 + sub;
    if (row >= nrows) return;
    const float4* xr = (const float4*)(X + (size_t)row * 64);
    float4 acc = {0.f, 0.f, 0.f, 0.f};
#pragma unroll
    for (int k4 = 0; k4 < 16; ++k4) {
        float4 xv = xr[k4];
#pragma unroll
        for (int j = 0; j < 4; ++j) {
            float xs = (j == 0) ? xv.x : (j == 1) ? xv.y : (j == 2) ? xv.z : xv.w;
            float4 wv = Ws[k4 * 4 + j][q];
            acc.x = fmaf(xs, wv.x, acc.x);
            acc.y = fmaf(xs, wv.y, acc.y);
            acc.z = fmaf(xs, wv.z, acc.z);
            acc.w = fmaf(xs, wv.w, acc.w);
        }
    }
    *(float4*)(Y + (size_t)row * 64 + q * 4) = acc;
}

// ---------------------------------------------------------------------------
// 5a) layer-1 gather + self-loop + bias + relu -> H
//     One wave per node. lane = (edge-group g = lane>>4) x (channel-quad q = lane&15)
// ---------------------------------------------------------------------------
__global__ void gather_l1_kernel(const int* __restrict__ rowptr,
                                 const int2* __restrict__ edgeRec,
                                 const float* __restrict__ XW,
                                 const float* __restrict__ dis, const float* __restrict__ b,
                                 float* __restrict__ H) {
    int node = blockIdx.x * (blockDim.x >> 6) + (threadIdx.x >> 6);
    if (node >= N_NODES) return;
    int lane = threadIdx.x & 63;
    int g = lane >> 4;
    int q = lane & 15;
    int beg = rowptr[node], end = rowptr[node + 1];

    float4 acc = {0.f, 0.f, 0.f, 0.f};
    for (int s = beg; s + g < end; s += 4) {
        int2  rec = edgeRec[s + g];
        float nv  = __int_as_float(rec.y);
        float4 xv = *(const float4*)(XW + (size_t)rec.x * 64 + q * 4);
        acc.x = fmaf(nv, xv.x, acc.x);
        acc.y = fmaf(nv, xv.y, acc.y);
        acc.z = fmaf(nv, xv.z, acc.z);
        acc.w = fmaf(nv, xv.w, acc.w);
    }
    acc.x += __shfl_xor(acc.x, 16, 64);
    acc.y += __shfl_xor(acc.y, 16, 64);
    acc.z += __shfl_xor(acc.z, 16, 64);
    acc.w += __shfl_xor(acc.w, 16, 64);
    acc.x += __shfl_xor(acc.x, 32, 64);
    acc.y += __shfl_xor(acc.y, 32, 64);
    acc.z += __shfl_xor(acc.z, 32, 64);
    acc.w += __shfl_xor(acc.w, 32, 64);

    if (g == 0) {
        float d  = dis[node];
        float dd = d * d;
        float4 xs = *(const float4*)(XW + (size_t)node * 64 + q * 4);
        float4 bb = *(const float4*)(b + q * 4);
        float4 v;
        v.x = fmaxf(fmaf(dd, xs.x, acc.x) + bb.x, 0.f);
        v.y = fmaxf(fmaf(dd, xs.y, acc.y) + bb.y, 0.f);
        v.z = fmaxf(fmaf(dd, xs.z, acc.z) + bb.z, 0.f);
        v.w = fmaxf(fmaf(dd, xs.w, acc.w) + bb.w, 0.f);
        *(float4*)(H + (size_t)node * 64 + q * 4) = v;
    }
}

// ---------------------------------------------------------------------------
// 5b) layer-2 gather + self-loop + bias + relu + (h @ Wout + bout) + tanh -> OUT
// ---------------------------------------------------------------------------
__global__ void gather_out_kernel(const int* __restrict__ rowptr,
                                  const int2* __restrict__ edgeRec,
                                  const float* __restrict__ XW,
                                  const float* __restrict__ dis, const float* __restrict__ b,
                                  const float* __restrict__ Wout, const float* __restrict__ bout,
                                  float* __restrict__ OUT) {
    __shared__ float Ws[64][OUT_CH];          // Ws[k][j] = Wout[k][j], 8 KB
    {
        int t = threadIdx.x;
        for (int i = t; i < 64 * OUT_CH / 4; i += 256)
            ((float4*)Ws)[i] = ((const float4*)Wout)[i];
        __syncthreads();
    }

    int node = blockIdx.x * (blockDim.x >> 6) + (threadIdx.x >> 6);
    if (node >= N_NODES) return;
    int lane = threadIdx.x & 63;
    int g = lane >> 4;
    int q = lane & 15;
    int beg = rowptr[node], end = rowptr[node + 1];

    float4 acc = {0.f, 0.f, 0.f, 0.f};
    for (int s = beg; s + g < end; s += 4) {
        int2  rec = edgeRec[s + g];
        float nv  = __int_as_float(rec.y);
        float4 xv = *(const float4*)(XW + (size_t)rec.x * 64 + q * 4);
        acc.x = fmaf(nv, xv.x, acc.x);
        acc.y = fmaf(nv, xv.y, acc.y);
        acc.z = fmaf(nv, xv.z, acc.z);
        acc.w = fmaf(nv, xv.w, acc.w);
    }
    acc.x += __shfl_xor(acc.x, 16, 64);
    acc.y += __shfl_xor(acc.y, 16, 64);
    acc.z += __shfl_xor(acc.z, 16, 64);
    acc.w += __shfl_xor(acc.w, 16, 64);
    acc.x += __shfl_xor(acc.x, 32, 64);
    acc.y += __shfl_xor(acc.y, 32, 64);
    acc.z += __shfl_xor(acc.z, 32, 64);
    acc.w += __shfl_xor(acc.w, 32, 64);

    // every lane now holds the reduced quad for channels 4q..4q+3
    float d  = dis[node];
    float dd = d * d;
    float4 xs = *(const float4*)(XW + (size_t)node * 64 + q * 4);
    float4 bb = *(const float4*)(b + q * 4);
    float4 h;
    h.x = fmaxf(fmaf(dd, xs.x, acc.x) + bb.x, 0.f);
    h.y = fmaxf(fmaf(dd, xs.y, acc.y) + bb.y, 0.f);
    h.z = fmaxf(fmaf(dd, xs.z, acc.z) + bb.z, 0.f);
    h.w = fmaxf(fmaf(dd, xs.w, acc.w) + bb.w, 0.f);

    // 64x32 matvec: lane L computes out[L&31] over k-half (L>>5)
    int j    = lane & 31;
    int half = lane >> 5;                     // 0: k=0..31, 1: k=32..63
    float partial = 0.f;
#pragma unroll
    for (int p = 0; p < 8; ++p) {
        int qp = half * 8 + p;                // source channel-quad
        float hx = __shfl(h.x, qp, 64);
        float hy = __shfl(h.y, qp, 64);
        float hz = __shfl(h.z, qp, 64);
        float hw = __shfl(h.w, qp, 64);
        int k = qp * 4;
        partial = fmaf(hx, Ws[k + 0][j], partial);
        partial = fmaf(hy, Ws[k + 1][j], partial);
        partial = fmaf(hz, Ws[k + 2][j], partial);
        partial = fmaf(hw, Ws[k + 3][j], partial);
    }
    partial += __shfl_xor(partial, 32, 64);
    if (lane < 32) {
        OUT[(size_t)node * OUT_CH + lane] = tanhf(partial + bout[lane]);
    }
}

// ---------------------------------------------------------------------------
extern "C" void kernel_launch(void* const* d_in, const int* in_sizes, int n_in,
                              void* d_out, int out_size, void* d_ws, size_t ws_size,
                              hipStream_t stream) {
    const float* x     = (const float*)d_in[0];
    const int*   eidx  = (const int*)  d_in[1];
    const float* ew    = (const float*)d_in[2];
    const float* W1    = (const float*)d_in[3];
    const float* b1    = (const float*)d_in[4];
    const float* W2    = (const float*)d_in[5];
    const float* b2    = (const float*)d_in[6];
    const float* Wout  = (const float*)d_in[7];
    const float* bout  = (const float*)d_in[8];
    float*       out   = (float*)d_out;

    const int* row = eidx;             // edge_index[0]
    const int* col = eidx + N_EDGES;   // edge_index[1]

    // workspace layout
    char*  ws   = (char*)d_ws;
    size_t offs = 0;
    auto alloc = [&](size_t bytes) {
        char* p = ws + offs;
        offs += (bytes + 1023) & ~(size_t)1023;
        return p;
    };
    unsigned long long* packed = (unsigned long long*)alloc((size_t)N_NODES * 8);
    float* dis       = (float*)alloc((size_t)N_NODES * sizeof(float));
    int*   rowptr    = (int*)  alloc((size_t)(N_NODES + 1) * sizeof(int));
    int*   blockSums = (int*)  alloc((size_t)SCAN_NB * sizeof(int));
    int2*  edgeRec   = (int2*) alloc((size_t)N_EDGES * sizeof(int2));
    float* xw        = (float*)alloc((size_t)N_NODES * GCN_CH * sizeof(float));
    float* h         = (float*)alloc((size_t)N_NODES * GCN_CH * sizeof(float));

    const int BLK = 256;
    const int gEdges  = (N_EDGES + BLK - 1) / BLK;
    const int gNodes  = (N_NODES + BLK - 1) / BLK;
    const int gGemm64 = (N_NODES + 15) / 16;   // 16 rows/block
    const int gGather = (N_NODES + 3) / 4;     // 4 nodes/block (1 wave each)

    // ---- graph preprocessing (once per call, shared by both layers) ----
    hipMemsetAsync(packed, 0, (size_t)N_NODES * 8, stream);
    deg_pack_kernel<<<gEdges, BLK, 0, stream>>>(col, ew, packed);
    scan1_kernel<<<SCAN_NB, SCAN_BLK, 0, stream>>>(packed, rowptr, blockSums, dis);
    scan2_kernel<<<1, 128, 0, stream>>>(blockSums);
    scan3_kernel<<<gNodes, BLK, 0, stream>>>(rowptr, blockSums);
    fill_kernel<<<gEdges, BLK, 0, stream>>>(row, col, ew, dis, rowptr, packed, edgeRec);

    // ---- layer 1 ----
    gemm64_kernel<<<gGemm64, BLK, 0, stream>>>(x, W1, xw, N_NODES);
    gather_l1_kernel<<<gGather, BLK, 0, stream>>>(rowptr, edgeRec, xw, dis, b1, h);

    // ---- layer 2 (gather fused with output projection) ----
    gemm64_kernel<<<gGemm64, BLK, 0, stream>>>(h, W2, xw, N_NODES);
    gather_out_kernel<<<gGather, BLK, 0, stream>>>(rowptr, edgeRec, xw, dis, b2,
                                                   Wout, bout, out);
}

// Round 6
// 339.374 us; speedup vs baseline: 2.4644x; 1.0756x over previous
//
#include <hip/hip_runtime.h>
#include <hip/hip_fp16.h>
#include <math.h>

#define N_NODES 100000
#define N_EDGES 1600000
#define IN_CH   64
#define GCN_CH  64
#define OUT_CH  32

#define CNT_SHIFT 42
#define W_SCALE   67108864.0f          // 2^26
#define W_INV     (1.0f / 67108864.0f)

#define SCAN_BLK   256
#define SCAN_ITEMS 4
#define SCAN_CHUNK (SCAN_BLK * SCAN_ITEMS)              // 1024
#define SCAN_NB    ((N_NODES + SCAN_CHUNK - 1) / SCAN_CHUNK)  // 98

// ---------------------------------------------------------------------------
// 1) fused histogram: packed[c] += (1<<42) | round(ew * 2^26)
// ---------------------------------------------------------------------------
__global__ void deg_pack_kernel(const int* __restrict__ col, const float* __restrict__ ew,
                                unsigned long long* __restrict__ packed) {
    int e = blockIdx.x * blockDim.x + threadIdx.x;
    if (e >= N_EDGES) return;
    int c = col[e];
    unsigned long long w = (unsigned long long)(ew[e] * W_SCALE + 0.5f);
    atomicAdd(&packed[c], (1ULL << CNT_SHIFT) | w);
}

// ---------------------------------------------------------------------------
// 2) scan of counts -> rowptr (exclusive); also dis = rsqrt(weight + 1)
// ---------------------------------------------------------------------------
__global__ void scan1_kernel(const unsigned long long* __restrict__ packed,
                             int* __restrict__ rowptr, int* __restrict__ blockSums,
                             float* __restrict__ dis) {
    __shared__ int sdata[SCAN_BLK];
    int t = threadIdx.x;
    int base = blockIdx.x * SCAN_CHUNK + t * SCAN_ITEMS;
    int v[SCAN_ITEMS];
    int sum = 0;
#pragma unroll
    for (int i = 0; i < SCAN_ITEMS; ++i) {
        int idx = base + i;
        unsigned long long p = (idx < N_NODES) ? packed[idx] : 0ULL;
        v[i] = (int)(p >> CNT_SHIFT);
        sum += v[i];
        if (idx < N_NODES) {
            float deg = (float)(p & ((1ULL << CNT_SHIFT) - 1)) * W_INV;
            dis[idx] = rsqrtf(deg + 1.0f);
        }
    }
    sdata[t] = sum;
    __syncthreads();
    for (int off = 1; off < SCAN_BLK; off <<= 1) {
        int x = (t >= off) ? sdata[t - off] : 0;
        __syncthreads();
        sdata[t] += x;
        __syncthreads();
    }
    int excl = sdata[t] - sum;
    if (t == SCAN_BLK - 1) blockSums[blockIdx.x] = sdata[t];
    int run = excl;
#pragma unroll
    for (int i = 0; i < SCAN_ITEMS; ++i) {
        int idx = base + i;
        if (idx < N_NODES) rowptr[idx] = run;
        run += v[i];
    }
}

__global__ void scan2_kernel(int* __restrict__ blockSums) {
    __shared__ int s[128];
    int t = threadIdx.x;
    int orig = (t < SCAN_NB) ? blockSums[t] : 0;
    s[t] = orig;
    __syncthreads();
    for (int off = 1; off < 128; off <<= 1) {
        int x = (t >= off) ? s[t - off] : 0;
        __syncthreads();
        s[t] += x;
        __syncthreads();
    }
    if (t < SCAN_NB) blockSums[t] = s[t] - orig;
}

__global__ void scan3_kernel(int* __restrict__ rowptr, const int* __restrict__ blockSums) {
    int i = blockIdx.x * blockDim.x + threadIdx.x;
    if (i < N_NODES) rowptr[i] += blockSums[i / SCAN_CHUNK];
    if (i == 0) rowptr[N_NODES] = N_EDGES;
}

// ---------------------------------------------------------------------------
// 3) bucket fill (cursor = count field of packed)
// ---------------------------------------------------------------------------
__global__ void fill_kernel(const int* __restrict__ row, const int* __restrict__ col,
                            const float* __restrict__ ew, const float* __restrict__ dis,
                            const int* __restrict__ rowptr,
                            unsigned long long* __restrict__ packed,
                            int2* __restrict__ edgeRec) {
    int e = blockIdx.x * blockDim.x + threadIdx.x;
    if (e >= N_EDGES) return;
    int r = row[e], c = col[e];
    unsigned long long old =
        atomicAdd(&packed[c], (unsigned long long)(-(long long)(1ULL << CNT_SHIFT)));
    int k = (int)(old >> CNT_SHIFT) - 1;
    int slot = rowptr[c] + k;
    float nv = dis[r] * ew[e] * dis[c];
    edgeRec[slot] = make_int2(r, __float_as_int(nv));
}

// ---------------------------------------------------------------------------
// 4) dense GEMM  Yh[N,64] = fp16( X[N,64] @ W[64,64] )  — fp32 in, fp16 out
// ---------------------------------------------------------------------------
__global__ void gemm64_f16_kernel(const float* __restrict__ X, const float* __restrict__ W,
                                  __half* __restrict__ Y, int nrows) {
    __shared__ float4 Ws[64][16];   // Ws[k][q] = W[k][4q..4q+3]
    int t = threadIdx.x;
    for (int i = t; i < 64 * 16; i += 256)
        ((float4*)Ws)[i] = ((const float4*)W)[i];
    __syncthreads();

    int q   = t & 15;
    int sub = t >> 4;               // 16 rows per block
    int row = blockIdx.x * 16 + sub;
    if (row >= nrows) return;
    const float4* xr = (const float4*)(X + (size_t)row * 64);
    float4 acc = {0.f, 0.f, 0.f, 0.f};
#pragma unroll
    for (int k4 = 0; k4 < 16; ++k4) {
        float4 xv = xr[k4];
#pragma unroll
        for (int j = 0; j < 4; ++j) {
            float xs = (j == 0) ? xv.x : (j == 1) ? xv.y : (j == 2) ? xv.z : xv.w;
            float4 wv = Ws[k4 * 4 + j][q];
            acc.x = fmaf(xs, wv.x, acc.x);
            acc.y = fmaf(xs, wv.y, acc.y);
            acc.z = fmaf(xs, wv.z, acc.z);
            acc.w = fmaf(xs, wv.w, acc.w);
        }
    }
    union { __half2 h[2]; float2 f; } u;
    u.h[0] = __floats2half2_rn(acc.x, acc.y);
    u.h[1] = __floats2half2_rn(acc.z, acc.w);
    *(float2*)(Y + (size_t)row * 64 + q * 4) = u.f;
}

// ---------------------------------------------------------------------------
// helper: load 8 fp16 channels (16 B) and fma into 8 fp32 accumulators
// ---------------------------------------------------------------------------
__device__ inline void fma8_f16(const __half* p, float nv, float* acc) {
    float4 raw = *(const float4*)p;
    const __half2* hp = (const __half2*)&raw;
#pragma unroll
    for (int i = 0; i < 4; ++i) {
        acc[2 * i + 0] = fmaf(nv, __low2float(hp[i]),  acc[2 * i + 0]);
        acc[2 * i + 1] = fmaf(nv, __high2float(hp[i]), acc[2 * i + 1]);
    }
}

// ---------------------------------------------------------------------------
// 5a) layer-1 gather + self-loop + bias + relu -> H (fp32)
//     One wave per node. lane = (edge-group g = lane>>3) x (channel-oct q = lane&7)
//     8 edges in flight, 8 fp16 channels (16 B) per lane.
// ---------------------------------------------------------------------------
__global__ void gather_l1_kernel(const int* __restrict__ rowptr,
                                 const int2* __restrict__ edgeRec,
                                 const __half* __restrict__ XWh,
                                 const float* __restrict__ dis, const float* __restrict__ b,
                                 float* __restrict__ H) {
    int node = blockIdx.x * (blockDim.x >> 6) + (threadIdx.x >> 6);
    if (node >= N_NODES) return;
    int lane = threadIdx.x & 63;
    int g = lane >> 3;          // edge group 0..7
    int q = lane & 7;           // channel oct
    int beg = rowptr[node], end = rowptr[node + 1];

    float acc[8] = {0.f, 0.f, 0.f, 0.f, 0.f, 0.f, 0.f, 0.f};
    for (int s = beg; s + g < end; s += 8) {
        int2  rec = edgeRec[s + g];
        float nv  = __int_as_float(rec.y);
        fma8_f16(XWh + (size_t)rec.x * 64 + q * 8, nv, acc);
    }
    // reduce across the 8 edge-groups (lane bits 3,4,5)
#pragma unroll
    for (int m = 8; m <= 32; m <<= 1)
#pragma unroll
        for (int i = 0; i < 8; ++i)
            acc[i] += __shfl_xor(acc[i], m, 64);

    if (g == 0) {
        float d  = dis[node];
        float dd = d * d;
        float4 raw = *(const float4*)(XWh + (size_t)node * 64 + q * 8);
        const __half2* hp = (const __half2*)&raw;
        float4 b0 = *(const float4*)(b + q * 8);
        float4 b1 = *(const float4*)(b + q * 8 + 4);
        float o[8];
        o[0] = fmaxf(fmaf(dd, __low2float(hp[0]),  acc[0]) + b0.x, 0.f);
        o[1] = fmaxf(fmaf(dd, __high2float(hp[0]), acc[1]) + b0.y, 0.f);
        o[2] = fmaxf(fmaf(dd, __low2float(hp[1]),  acc[2]) + b0.z, 0.f);
        o[3] = fmaxf(fmaf(dd, __high2float(hp[1]), acc[3]) + b0.w, 0.f);
        o[4] = fmaxf(fmaf(dd, __low2float(hp[2]),  acc[4]) + b1.x, 0.f);
        o[5] = fmaxf(fmaf(dd, __high2float(hp[2]), acc[5]) + b1.y, 0.f);
        o[6] = fmaxf(fmaf(dd, __low2float(hp[3]),  acc[6]) + b1.z, 0.f);
        o[7] = fmaxf(fmaf(dd, __high2float(hp[3]), acc[7]) + b1.w, 0.f);
        *(float4*)(H + (size_t)node * 64 + q * 8)     = make_float4(o[0], o[1], o[2], o[3]);
        *(float4*)(H + (size_t)node * 64 + q * 8 + 4) = make_float4(o[4], o[5], o[6], o[7]);
    }
}

// ---------------------------------------------------------------------------
// 5b) layer-2 gather + self-loop + bias + relu + (h @ Wout + bout) + tanh -> OUT
// ---------------------------------------------------------------------------
__global__ void gather_out_kernel(const int* __restrict__ rowptr,
                                  const int2* __restrict__ edgeRec,
                                  const __half* __restrict__ XWh,
                                  const float* __restrict__ dis, const float* __restrict__ b,
                                  const float* __restrict__ Wout, const float* __restrict__ bout,
                                  float* __restrict__ OUT) {
    __shared__ float Ws[64][OUT_CH];          // Ws[k][j] = Wout[k][j], 8 KB
    {
        int t = threadIdx.x;
        for (int i = t; i < 64 * OUT_CH / 4; i += 256)
            ((float4*)Ws)[i] = ((const float4*)Wout)[i];
        __syncthreads();
    }

    int node = blockIdx.x * (blockDim.x >> 6) + (threadIdx.x >> 6);
    if (node >= N_NODES) return;
    int lane = threadIdx.x & 63;
    int g = lane >> 3;
    int q = lane & 7;
    int beg = rowptr[node], end = rowptr[node + 1];

    float acc[8] = {0.f, 0.f, 0.f, 0.f, 0.f, 0.f, 0.f, 0.f};
    for (int s = beg; s + g < end; s += 8) {
        int2  rec = edgeRec[s + g];
        float nv  = __int_as_float(rec.y);
        fma8_f16(XWh + (size_t)rec.x * 64 + q * 8, nv, acc);
    }
#pragma unroll
    for (int m = 8; m <= 32; m <<= 1)
#pragma unroll
        for (int i = 0; i < 8; ++i)
            acc[i] += __shfl_xor(acc[i], m, 64);

    // every lane now holds the reduced oct for channels 8q..8q+7
    float d  = dis[node];
    float dd = d * d;
    float4 raw = *(const float4*)(XWh + (size_t)node * 64 + q * 8);
    const __half2* hp = (const __half2*)&raw;
    float4 b0 = *(const float4*)(b + q * 8);
    float4 b1 = *(const float4*)(b + q * 8 + 4);
    float h[8];
    h[0] = fmaxf(fmaf(dd, __low2float(hp[0]),  acc[0]) + b0.x, 0.f);
    h[1] = fmaxf(fmaf(dd, __high2float(hp[0]), acc[1]) + b0.y, 0.f);
    h[2] = fmaxf(fmaf(dd, __low2float(hp[1]),  acc[2]) + b0.z, 0.f);
    h[3] = fmaxf(fmaf(dd, __high2float(hp[1]), acc[3]) + b0.w, 0.f);
    h[4] = fmaxf(fmaf(dd, __low2float(hp[2]),  acc[4]) + b1.x, 0.f);
    h[5] = fmaxf(fmaf(dd, __high2float(hp[2]), acc[5]) + b1.y, 0.f);
    h[6] = fmaxf(fmaf(dd, __low2float(hp[3]),  acc[6]) + b1.z, 0.f);
    h[7] = fmaxf(fmaf(dd, __high2float(hp[3]), acc[7]) + b1.w, 0.f);

    // 64x32 matvec: lane L computes out[L&31] over k-half (L>>5)
    int j    = lane & 31;
    int half = lane >> 5;                     // 0: k=0..31, 1: k=32..63
    float partial = 0.f;
#pragma unroll
    for (int p = 0; p < 4; ++p) {
        int qp = half * 4 + p;                // source channel-oct (lane qp has it)
#pragma unroll
        for (int i = 0; i < 8; ++i) {
            float hv = __shfl(h[i], qp, 64);
            partial = fmaf(hv, Ws[qp * 8 + i][j], partial);
        }
    }
    partial += __shfl_xor(partial, 32, 64);
    if (lane < 32) {
        OUT[(size_t)node * OUT_CH + lane] = tanhf(partial + bout[lane]);
    }
}

// ---------------------------------------------------------------------------
extern "C" void kernel_launch(void* const* d_in, const int* in_sizes, int n_in,
                              void* d_out, int out_size, void* d_ws, size_t ws_size,
                              hipStream_t stream) {
    const float* x     = (const float*)d_in[0];
    const int*   eidx  = (const int*)  d_in[1];
    const float* ew    = (const float*)d_in[2];
    const float* W1    = (const float*)d_in[3];
    const float* b1    = (const float*)d_in[4];
    const float* W2    = (const float*)d_in[5];
    const float* b2    = (const float*)d_in[6];
    const float* Wout  = (const float*)d_in[7];
    const float* bout  = (const float*)d_in[8];
    float*       out   = (float*)d_out;

    const int* row = eidx;             // edge_index[0]
    const int* col = eidx + N_EDGES;   // edge_index[1]

    // workspace layout
    char*  ws   = (char*)d_ws;
    size_t offs = 0;
    auto alloc = [&](size_t bytes) {
        char* p = ws + offs;
        offs += (bytes + 1023) & ~(size_t)1023;
        return p;
    };
    unsigned long long* packed = (unsigned long long*)alloc((size_t)N_NODES * 8);
    float*  dis       = (float*) alloc((size_t)N_NODES * sizeof(float));
    int*    rowptr    = (int*)   alloc((size_t)(N_NODES + 1) * sizeof(int));
    int*    blockSums = (int*)   alloc((size_t)SCAN_NB * sizeof(int));
    int2*   edgeRec   = (int2*)  alloc((size_t)N_EDGES * sizeof(int2));
    __half* xwh       = (__half*)alloc((size_t)N_NODES * GCN_CH * sizeof(__half));
    float*  h         = (float*) alloc((size_t)N_NODES * GCN_CH * sizeof(float));

    const int BLK = 256;
    const int gEdges  = (N_EDGES + BLK - 1) / BLK;
    const int gNodes  = (N_NODES + BLK - 1) / BLK;
    const int gGemm64 = (N_NODES + 15) / 16;   // 16 rows/block
    const int gGather = (N_NODES + 3) / 4;     // 4 nodes/block (1 wave each)

    // ---- graph preprocessing (once per call, shared by both layers) ----
    hipMemsetAsync(packed, 0, (size_t)N_NODES * 8, stream);
    deg_pack_kernel<<<gEdges, BLK, 0, stream>>>(col, ew, packed);
    scan1_kernel<<<SCAN_NB, SCAN_BLK, 0, stream>>>(packed, rowptr, blockSums, dis);
    scan2_kernel<<<1, 128, 0, stream>>>(blockSums);
    scan3_kernel<<<gNodes, BLK, 0, stream>>>(rowptr, blockSums);
    fill_kernel<<<gEdges, BLK, 0, stream>>>(row, col, ew, dis, rowptr, packed, edgeRec);

    // ---- layer 1 ----
    gemm64_f16_kernel<<<gGemm64, BLK, 0, stream>>>(x, W1, xwh, N_NODES);
    gather_l1_kernel<<<gGather, BLK, 0, stream>>>(rowptr, edgeRec, xwh, dis, b1, h);

    // ---- layer 2 (gather fused with output projection) ----
    gemm64_f16_kernel<<<gGemm64, BLK, 0, stream>>>(h, W2, xwh, N_NODES);
    gather_out_kernel<<<gGather, BLK, 0, stream>>>(rowptr, edgeRec, xwh, dis, b2,
                                                   Wout, bout, out);
}